// Round 10
// baseline (5768.556 us; speedup 1.0000x reference)
//
#include <hip/hip_runtime.h>
#include <cstdint>
#include <cstddef>

typedef __attribute__((ext_vector_type(8))) short short8;
typedef __attribute__((ext_vector_type(4))) float floatx4;
typedef unsigned short u16;
typedef unsigned long long u64;

#define NSTEP 256

__device__ __forceinline__ unsigned f2b_rne(float x) {
  unsigned u = __builtin_bit_cast(unsigned, x);
  return (u + 0x7fffu + ((u >> 16) & 1u)) >> 16;
}
__device__ __forceinline__ float b2f(u16 b) {
  unsigned u = ((unsigned)b) << 16;
  return __builtin_bit_cast(float, u);
}
__device__ __forceinline__ float sigf(float x) {
  x = fminf(fmaxf(x, -30.f), 30.f);
  return __builtin_amdgcn_rcpf(1.f + __expf(-x));
}
__device__ __forceinline__ float tanhf_fast(float x) {
  x = fminf(fmaxf(x, -15.f), 15.f);
  float e = __expf(2.f * x);
  return (e - 1.f) * __builtin_amdgcn_rcpf(e + 1.f);
}

// agent-scope relaxed atomics: execute at the coherence point, bypass L1/L2.
__device__ __forceinline__ unsigned ald(const unsigned* p) {
  return __hip_atomic_load(p, __ATOMIC_RELAXED, __HIP_MEMORY_SCOPE_AGENT);
}
__device__ __forceinline__ void ast(unsigned* p, unsigned v) {
  __hip_atomic_store(p, v, __ATOMIC_RELAXED, __HIP_MEMORY_SCOPE_AGENT);
}

// ---------------- init: zero h rows t=0 (u32 view) ----------------
__global__ void init_kernel(unsigned* h0, unsigned* h1) {
  int i = blockIdx.x * blockDim.x + threadIdx.x;
  if (i < 32768) { h0[i] = 0; h1[i] = 0; }
}

// ---------------- init2: zero flag region ----------------
__global__ void init2_kernel(unsigned* fl) {
  int i = blockIdx.x * blockDim.x + threadIdx.x;
  if (i < 2048) fl[i] = 0;
}

// ---------------- fp32 -> bf16 cast (vectorized x4) ----------------
__global__ void cast_kernel(const float* __restrict__ in, u16* __restrict__ out, int n4) {
  int i = blockIdx.x * blockDim.x + threadIdx.x;
  int stride = gridDim.x * blockDim.x;
  for (; i < n4; i += stride) {
    float4 v = ((const float4*)in)[i];
    unsigned lo = f2b_rne(v.x) | (f2b_rne(v.y) << 16);
    unsigned hi = f2b_rne(v.z) | (f2b_rne(v.w) << 16);
    ((uint2*)out)[i] = make_uint2(lo, hi);
  }
}

// per-wave K-quarter GEMM accumulate over one blocked h row.
// H layout (dwords per 32768-dword row): word(b,j) at (j>>4)*512 + b*8 + ((j&15)>>1).
// Round-8 proven scheduling: issue ALL 32 fragment loads, PIN with asm("+v"),
// then run all 128 MFMAs -> one pipelined MALL latency exposure.
#define GEMM_Q(HROW, W)                                                        \
  {                                                                            \
    short8 a_[8][4];                                                           \
    _Pragma("unroll")                                                          \
    for (int c_ = 0; c_ < 8; ++c_) {                                           \
      int k_ = kq0 + c_ * 32 + q * 8;                                          \
      const unsigned* base_ = (HROW) + (k_ >> 4) * 512 + ((k_ & 15) >> 1);     \
      _Pragma("unroll")                                                        \
      for (int m_ = 0; m_ < 4; ++m_)                                           \
        a_[c_][m_] = *(const short8*)(base_ + (m_ * 16 + n16) * 8);            \
    }                                                                          \
    _Pragma("unroll")                                                          \
    for (int c_ = 0; c_ < 8; ++c_)                                             \
      _Pragma("unroll")                                                        \
      for (int m_ = 0; m_ < 4; ++m_)                                           \
        asm volatile("" : "+v"(a_[c_][m_]));                                   \
    _Pragma("unroll")                                                          \
    for (int c_ = 0; c_ < 8; ++c_)                                             \
      _Pragma("unroll")                                                        \
      for (int m_ = 0; m_ < 4; ++m_)                                           \
        _Pragma("unroll")                                                      \
        for (int g_ = 0; g_ < 4; ++g_)                                         \
          acc[m_][g_] = __builtin_amdgcn_mfma_f32_16x16x32_bf16(a_[c_][m_], (W)[g_][c_], acc[m_][g_], 0, 0, 0); \
  }

// same, but A is a row-major [64][1024] bf16 block (X rows; u16* base).
#define GEMM_QX(XROW, W)                                                       \
  {                                                                            \
    short8 a_[8][4];                                                           \
    _Pragma("unroll")                                                          \
    for (int c_ = 0; c_ < 8; ++c_) {                                           \
      int k_ = kq0 + c_ * 32 + q * 8;                                          \
      _Pragma("unroll")                                                        \
      for (int m_ = 0; m_ < 4; ++m_)                                           \
        a_[c_][m_] = *(const short8*)((XROW) + (size_t)(m_ * 16 + n16) * 1024 + k_); \
    }                                                                          \
    _Pragma("unroll")                                                          \
    for (int c_ = 0; c_ < 8; ++c_)                                             \
      _Pragma("unroll")                                                        \
      for (int m_ = 0; m_ < 4; ++m_)                                           \
        asm volatile("" : "+v"(a_[c_][m_]));                                   \
    _Pragma("unroll")                                                          \
    for (int c_ = 0; c_ < 8; ++c_)                                             \
      _Pragma("unroll")                                                        \
      for (int m_ = 0; m_ < 4; ++m_)                                           \
        _Pragma("unroll")                                                      \
        for (int g_ = 0; g_ < 4; ++g_)                                         \
          acc[m_][g_] = __builtin_amdgcn_mfma_f32_16x16x32_bf16(a_[c_][m_], (W)[g_][c_], acc[m_][g_], 0, 0, 0); \
  }

// cross-wave K reduction via LDS within each 4-wave HALF (redh = this half's
// buffer, wq = wave index in half). ONE barrier, executed by all 512 threads.
#define REDUCE_TOT()                                                           \
  _Pragma("unroll")                                                            \
  for (int m_ = 0; m_ < 4; ++m_) {                                             \
    if (m_ != wq) {                                                            \
      int slot_ = (m_ - (m_ > wq ? 1 : 0)) * 4;                                \
      _Pragma("unroll")                                                        \
      for (int g_ = 0; g_ < 4; ++g_)                                           \
        *(floatx4*)&redh[wq][slot_ + g_][lane * 4] = acc[m_][g_];              \
    }                                                                          \
  }                                                                            \
  __syncthreads();                                                             \
  _Pragma("unroll")                                                            \
  for (int g_ = 0; g_ < 4; ++g_) tot[g_] = acc[wq][g_];                        \
  _Pragma("unroll")                                                            \
  for (int w2_ = 0; w2_ < 4; ++w2_) {                                          \
    if (w2_ != wq) {                                                           \
      int slot_ = (wq - (wq > w2_ ? 1 : 0)) * 4;                               \
      _Pragma("unroll")                                                        \
      for (int g_ = 0; g_ < 4; ++g_)                                           \
        tot[g_] += *(const floatx4*)&redh[w2_][slot_ + g_][lane * 4];          \
    }                                                                          \
  }

// distributed flag barrier: flag[i] at FL[i*8] (32B stride). One writer per
// flag (atomic store, no RMW chain); wave-0's 64 lanes poll 64 flags in
// parallel and combine with __all.
#define POLL1(FLA, TGTA)                                                       \
  if (wv == 0) {                                                               \
    int spins_ = 0;                                                            \
    for (;;) {                                                                 \
      unsigned va_ = ald((FLA) + lane * 8);                                    \
      if (__all((int)(va_ >= (TGTA)))) break;                                  \
      __builtin_amdgcn_s_sleep(1);                                             \
      if (++spins_ > (1 << 17)) break;                                         \
    }                                                                          \
  }
#define POLL2(FLA, TGTA, FLB, TGTB)                                            \
  if (wv == 0) {                                                               \
    int spins_ = 0;                                                            \
    for (;;) {                                                                 \
      unsigned va_ = ald((FLA) + lane * 8);                                    \
      unsigned vb_ = ald((FLB) + lane * 8);                                    \
      if (__all((int)((va_ >= (TGTA)) & (vb_ >= (TGTB))))) break;              \
      __builtin_amdgcn_s_sleep(1);                                             \
      if (++spins_ > (1 << 17)) break;                                         \
    }                                                                          \
  }

// ---------------- fused persistent 2-group x 2-half LSTM pipeline ----------
// 128 WGs x 512 threads (8 waves). grp = blockIdx>>6: 0=A (layer 0), 1=B
// (layer 1). Within each WG: waves 0-3 = L-half (recurrence, Wh resident),
// waves 4-7 = P-half (input-GEMM producer, Wx resident).
//   A: L0 consumes gbuf[t&1] = X[t]@Wx0^T; P0 computes X[t+1]@Wx0^T into
//      gbuf[(t+1)&1]. gemm_nt and the global G buffer are GONE.
//   B: L1 consumes gbuf[t&1] = h0(t+1)@Wx1^T; P1 computes h0(t+2)@Wx1^T.
//      The global G1 ring + its scattered atomics (round-8's biggest write
//      amplifier, round-9's regression source) are GONE.
// The G exchange is an LDS double-buffer synchronized by the existing
// per-step __syncthreads — zero global traffic, zero flags, no polling.
// Cross-WG sync: ONLY the proven fl0/fl1 flag arrays + h-row atomic stores
// (byte-identical protocol to rounds 5/8). Gating: A(t): fl0>=t. B(t):
// fl1>=t & fl0>=min(t+2,256). A never waits on B -> no deadlock cycles.
__global__ __launch_bounds__(512, 2) void lstm_fused(
    const u16* __restrict__ Wh0b,   // [4096][1024] bf16
    const u16* __restrict__ Wx0b,   // [4096][1024] bf16
    const u16* __restrict__ Wx1b,   // [4096][1024] bf16
    const u16* __restrict__ Wh1b,   // [4096][1024] bf16
    const u16* __restrict__ Xb,     // [16384][1024] bf16 row-major
    const float* __restrict__ bias, // [2][4096]
    unsigned* H0u,                  // u32 blocked, 257 rows
    unsigned* H1u,
    unsigned* FL,                   // fl0 @0, fl1 @512 (dwords, stride 8)
    float* __restrict__ outp,       // [256*64*1024] fp32 (layer-1 output)
    float* __restrict__ hf,         // [2*64*1024] fp32
    float* __restrict__ cf) {       // [2*64*1024] fp32
  __shared__ float redL[4][12][256];
  __shared__ float redP[4][12][256];
  __shared__ float gbuf[2][4][64][18];  // [slot][gate][b][j16] (+2 pad: banks)
  const int tid = threadIdx.x;
  const int wv = tid >> 6;          // 0..7
  const int half = wv >> 2;         // 0 = L (recurrence), 1 = P (producer)
  const int wq = wv & 3;            // K-quarter index within half
  const int lane = tid & 63;
  const int q = lane >> 4;
  const int n16 = lane & 15;
  const int grp = blockIdx.x >> 6;  // 0 = layer 0, 1 = layer 1
  const int jb = blockIdx.x & 63;
  const int jg = (jb << 4) + n16;
  const int kq0 = wq << 8;
  unsigned* fl0 = FL;
  unsigned* fl1 = FL + 512;
  unsigned* flme = grp ? fl1 : fl0;
  unsigned* Hme = grp ? H1u : H0u;  // L-half state buffer
  float (*redh)[12][256] = half ? redP : redL;
  const floatx4 vzero = {0.f, 0.f, 0.f, 0.f};

  // per-wave resident weights: L-half -> Wh(layer), P-half -> Wx(layer)
  const u16* Wmy = half ? (grp ? Wx1b : Wx0b) : (grp ? Wh1b : Wh0b);
  short8 wf[4][8];
#pragma unroll
  for (int g = 0; g < 4; ++g)
#pragma unroll
    for (int c = 0; c < 8; ++c)
      wf[g][c] = *(const short8*)(Wmy + (size_t)(g * 1024 + jg) * 1024 + kq0 + c * 32 + q * 8);
#pragma unroll
  for (int g = 0; g < 4; ++g)
#pragma unroll
    for (int c = 0; c < 8; ++c) asm volatile("" : "+v"(wf[g][c]));

  float bs[4] = {0.f, 0.f, 0.f, 0.f};
  if (half == 0) {
#pragma unroll
    for (int g = 0; g < 4; ++g) bs[g] = bias[grp * 4096 + g * 1024 + jg];
  }
  float cst[4] = {0.f, 0.f, 0.f, 0.f};

  // ---------------- prologue: P-half fills gbuf[0] ----------------
  if (grp == 1) { POLL1(fl0, 1u); }  // h0 row 1 must exist for G1[0]
  __syncthreads();
  {
    floatx4 acc[4][4];
#pragma unroll
    for (int m = 0; m < 4; ++m)
#pragma unroll
      for (int g = 0; g < 4; ++g) acc[m][g] = vzero;
    if (half == 1) {
      if (grp == 0) { GEMM_QX(Xb, wf); }                 // X row-block 0
      else          { GEMM_Q(H0u + 32768, wf); }         // h0 row 1
    }
    floatx4 tot[4];
    REDUCE_TOT();
    if (half == 1) {
#pragma unroll
      for (int r = 0; r < 4; ++r) {
        int b = wq * 16 + q * 4 + r;
#pragma unroll
        for (int g = 0; g < 4; ++g) gbuf[0][g][b][n16] = tot[g][r];
      }
    }
  }
  // step-0 top barrier (below) publishes gbuf[0] to the L-half

  for (int t = 0; t < NSTEP; ++t) {
    if (grp == 0) {
      POLL1(fl0, (unsigned)t);
    } else {
      unsigned t0 = (unsigned)((t + 2 > NSTEP) ? NSTEP : t + 2);
      POLL2(fl1, (unsigned)t, fl0, t0);
    }
    __syncthreads();

    floatx4 acc[4][4];
#pragma unroll
    for (int m = 0; m < 4; ++m)
#pragma unroll
      for (int g = 0; g < 4; ++g) acc[m][g] = vzero;

    if (half == 0) {
      GEMM_Q(Hme + (size_t)t * 32768, wf);               // own h row t
    } else if (t + 1 < NSTEP) {
      if (grp == 0) { GEMM_QX(Xb + (size_t)(t + 1) * 65536, wf); }   // X t+1
      else          { GEMM_Q(H0u + (size_t)(t + 2) * 32768, wf); }   // h0 t+2
    }

    floatx4 tot[4];
    REDUCE_TOT();

    float hsv[4];
    if (half == 0) {
      // gates: gf from LDS (written by P during step t-1; barrier-published)
      unsigned* hnext = Hme + (size_t)(t + 1) * 32768 + jb * 512;
#pragma unroll
      for (int r = 0; r < 4; ++r) {
        int b = wq * 16 + q * 4 + r;
        float pi = tot[0][r] + gbuf[t & 1][0][b][n16] + bs[0];
        float pf = tot[1][r] + gbuf[t & 1][1][b][n16] + bs[1];
        float po = tot[2][r] + gbuf[t & 1][2][b][n16] + bs[2];
        float pc = tot[3][r] + gbuf[t & 1][3][b][n16] + bs[3];
        float cn = sigf(pf) * cst[r] + sigf(pi) * tanhf_fast(pc);
        float h = sigf(po) * tanhf_fast(cn);
        cst[r] = cn;
        hsv[r] = h;
        unsigned hv = f2b_rne(h);
        unsigned pv = (unsigned)__shfl_xor((int)hv, 1);
        if (!(n16 & 1)) ast(hnext + b * 8 + (n16 >> 1), hv | (pv << 16));
      }
    } else if (t + 1 < NSTEP) {
#pragma unroll
      for (int r = 0; r < 4; ++r) {
        int b = wq * 16 + q * 4 + r;
#pragma unroll
        for (int g = 0; g < 4; ++g) gbuf[(t + 1) & 1][g][b][n16] = tot[g][r];
      }
    }

    __syncthreads();  // drains h atomic stores; publishes gbuf writes
    if (tid == 0) ast(flme + jb * 8, (unsigned)(t + 1));

    // tails (off critical path)
    if (half == 0) {
      if (grp == 1) {
#pragma unroll
        for (int r = 0; r < 4; ++r) {
          int b = wq * 16 + q * 4 + r;
          outp[((size_t)t * 64 + b) * 1024 + jg] = hsv[r];
        }
      }
      if (t == NSTEP - 1) {
#pragma unroll
        for (int r = 0; r < 4; ++r) {
          int b = wq * 16 + q * 4 + r;
          hf[grp * 65536 + b * 1024 + jg] = hsv[r];
          cf[grp * 65536 + b * 1024 + jg] = cst[r];
        }
      }
    }
  }
}

// ---------------- launch ----------------
extern "C" void kernel_launch(void* const* d_in, const int* in_sizes, int n_in,
                              void* d_out, int out_size, void* d_ws, size_t ws_size,
                              hipStream_t stream) {
  const float* X  = (const float*)d_in[0];   // [256][64][1024]
  const float* Wx = (const float*)d_in[1];   // [2][4096][1024]
  const float* Wh = (const float*)d_in[2];   // [2][4096][1024]
  const float* b  = (const float*)d_in[3];   // [2][4096]
  float* out = (float*)d_out;

  char* ws = (char*)d_ws;
  u16* Xbf  = (u16*)(ws);                         // 33,554,432 B (P0 reads it)
  u16* Wxbf = (u16*)(ws + 33554432);              // 16,777,216 B
  u16* Whbf = (u16*)(ws + 50331648);              // 16,777,216 B
  unsigned* H0 = (unsigned*)(ws + 67108864);      // 33,685,504 B (257*131072)
  unsigned* H1 = (unsigned*)(ws + 100794368);     // 33,685,504 B
  unsigned* FL = (unsigned*)(ws + 134479872);     // flags, 8 KB

  float* out_seq = out;                // 16,777,216 floats
  float* Hf = out + 16777216;          // 131,072 floats
  float* Cf = out + 16777216 + 131072; // 131,072 floats

  init_kernel<<<128, 256, 0, stream>>>(H0, H1);
  init2_kernel<<<8, 256, 0, stream>>>(FL);
  cast_kernel<<<2048, 256, 0, stream>>>(X, Xbf, 16777216 / 4);
  cast_kernel<<<2048, 256, 0, stream>>>(Wx, Wxbf, 8388608 / 4);
  cast_kernel<<<2048, 256, 0, stream>>>(Wh, Whbf, 8388608 / 4);

  // fused pipeline: 128 WGs x 512 threads; A = {L0 | P0}, B = {L1 | P1};
  // G exchanged through LDS double-buffers (no global G traffic at all).
  lstm_fused<<<128, 512, 0, stream>>>(Whbf, Wxbf, Wxbf + 4194304, Whbf + 4194304,
                                      Xbf, b, H0, H1, FL, out_seq, Hf, Cf);
}

// Round 11
// 1890.652 us; speedup vs baseline: 3.0511x; 3.0511x over previous
//
#include <hip/hip_runtime.h>
#include <cstdint>
#include <cstddef>

typedef __attribute__((ext_vector_type(8))) short short8;
typedef __attribute__((ext_vector_type(4))) float floatx4;
typedef unsigned short u16;
typedef unsigned long long u64;

#define NSTEP 256

__device__ __forceinline__ unsigned f2b_rne(float x) {
  unsigned u = __builtin_bit_cast(unsigned, x);
  return (u + 0x7fffu + ((u >> 16) & 1u)) >> 16;
}
__device__ __forceinline__ float b2f(u16 b) {
  unsigned u = ((unsigned)b) << 16;
  return __builtin_bit_cast(float, u);
}
__device__ __forceinline__ float sigf(float x) {
  x = fminf(fmaxf(x, -30.f), 30.f);
  return __builtin_amdgcn_rcpf(1.f + __expf(-x));
}
__device__ __forceinline__ float tanhf_fast(float x) {
  x = fminf(fmaxf(x, -15.f), 15.f);
  float e = __expf(2.f * x);
  return (e - 1.f) * __builtin_amdgcn_rcpf(e + 1.f);
}

// agent-scope relaxed atomics: execute at the coherence point, bypass L1/L2.
__device__ __forceinline__ unsigned ald(const unsigned* p) {
  return __hip_atomic_load(p, __ATOMIC_RELAXED, __HIP_MEMORY_SCOPE_AGENT);
}
__device__ __forceinline__ void ast(unsigned* p, unsigned v) {
  __hip_atomic_store(p, v, __ATOMIC_RELAXED, __HIP_MEMORY_SCOPE_AGENT);
}

// ---------------- init: zero h rows t=0 (u32 view) ----------------
__global__ void init_kernel(unsigned* h0, unsigned* h1) {
  int i = blockIdx.x * blockDim.x + threadIdx.x;
  if (i < 32768) { h0[i] = 0; h1[i] = 0; }
}

// ---------------- init2: zero flag region (runs AFTER casts/gemm, region
// overlays the dead Xbf buffer) ----------------
__global__ void init2_kernel(unsigned* fl) {
  int i = blockIdx.x * blockDim.x + threadIdx.x;
  if (i < 1536) fl[i] = 0;
}

// ---------------- fp32 -> bf16 cast (vectorized x4) ----------------
__global__ void cast_kernel(const float* __restrict__ in, u16* __restrict__ out, int n4) {
  int i = blockIdx.x * blockDim.x + threadIdx.x;
  int stride = gridDim.x * blockDim.x;
  for (; i < n4; i += stride) {
    float4 v = ((const float4*)in)[i];
    unsigned lo = f2b_rne(v.x) | (f2b_rne(v.y) << 16);
    unsigned hi = f2b_rne(v.z) | (f2b_rne(v.w) << 16);
    ((uint2*)out)[i] = make_uint2(lo, hi);
  }
}

// ---------------- big NT GEMM: C[16384][4096] bf16 = A[16384][1024] @ B[4096][1024]^T
__global__ __launch_bounds__(256) void gemm_nt(
    const u16* __restrict__ A, const u16* __restrict__ B, u16* __restrict__ C) {
  __shared__ u16 As[128 * 32];
  __shared__ u16 Bs[128 * 32];
  const int bid = blockIdx.x;
  const int m_blk = (bid >> 5) << 7;
  const int n_blk = (bid & 31) << 7;
  const int tid = threadIdx.x;
  const int wv = tid >> 6, lane = tid & 63;
  const int q = lane >> 4, n16 = lane & 15;
  const int m0w = (wv >> 1) << 6, n0w = (wv & 1) << 6;

  const floatx4 vzero = {0.f, 0.f, 0.f, 0.f};
  floatx4 acc[4][4];
#pragma unroll
  for (int mt = 0; mt < 4; ++mt)
#pragma unroll
    for (int nt = 0; nt < 4; ++nt) acc[mt][nt] = vzero;

  for (int k0 = 0; k0 < 1024; k0 += 32) {
#pragma unroll
    for (int i = 0; i < 2; ++i) {
      int s = i * 256 + tid;           // slot 0..511
      int r = s >> 2, kk = (s & 3) << 3;
      int m = m_blk + r, k = k0 + kk;
      size_t a_off = (size_t)m * 1024 + k;
      size_t b_off = (size_t)(n_blk + r) * 1024 + k;
      __builtin_amdgcn_global_load_lds(
          (const __attribute__((address_space(1))) unsigned int*)(A + a_off),
          (__attribute__((address_space(3))) unsigned int*)(As + (size_t)(i * 256 + wv * 64) * 8),
          16, 0, 0);
      __builtin_amdgcn_global_load_lds(
          (const __attribute__((address_space(1))) unsigned int*)(B + b_off),
          (__attribute__((address_space(3))) unsigned int*)(Bs + (size_t)(i * 256 + wv * 64) * 8),
          16, 0, 0);
    }
    __syncthreads();
    short8 af[4], bf[4];
#pragma unroll
    for (int mt = 0; mt < 4; ++mt)
      af[mt] = *(const short8*)(As + (m0w + mt * 16 + n16) * 32 + q * 8);
#pragma unroll
    for (int nt = 0; nt < 4; ++nt)
      bf[nt] = *(const short8*)(Bs + (n0w + nt * 16 + n16) * 32 + q * 8);
#pragma unroll
    for (int mt = 0; mt < 4; ++mt)
#pragma unroll
      for (int nt = 0; nt < 4; ++nt)
        acc[mt][nt] = __builtin_amdgcn_mfma_f32_16x16x32_bf16(af[mt], bf[nt], acc[mt][nt], 0, 0, 0);
    __syncthreads();
  }
#pragma unroll
  for (int mt = 0; mt < 4; ++mt)
#pragma unroll
    for (int nt = 0; nt < 4; ++nt)
#pragma unroll
      for (int r = 0; r < 4; ++r) {
        int m = m_blk + m0w + mt * 16 + q * 4 + r;
        int n = n_blk + n0w + nt * 16 + n16;
        C[(size_t)m * 4096 + n] = (u16)f2b_rne(acc[mt][nt][r]);
      }
}

// per-wave K-quarter GEMM accumulate over one blocked h row.
// H layout (dwords per 32768-dword row): word(b,j) at (j>>4)*512 + b*8 + ((j&15)>>1).
// Round-8 scheduling: issue ALL 32 fragment loads first, then PIN each value
// with asm("+v") (forces 128 VGPRs of in-flight fragments; grid is 192 WGs on
// 256 CUs -> occupancy is grid-bound, registers are free), then run all 128
// MFMAs. The per-pin waitcnts resolve as vmcnt(31..0) -> one pipelined MALL
// latency instead of ~8 serialized round trips.
// INVARIANT (rounds 4/5, 9/10): weight residency + this load batch need the
// full 512-VGPR budget -> 256-thread blocks, __launch_bounds__(256, 1) ONLY.
#define GEMM_Q(HROW, W)                                                        \
  {                                                                            \
    short8 a_[8][4];                                                           \
    _Pragma("unroll")                                                          \
    for (int c_ = 0; c_ < 8; ++c_) {                                           \
      int k_ = kq0 + c_ * 32 + q * 8;                                          \
      const unsigned* base_ = (HROW) + (k_ >> 4) * 512 + ((k_ & 15) >> 1);     \
      _Pragma("unroll")                                                        \
      for (int m_ = 0; m_ < 4; ++m_)                                           \
        a_[c_][m_] = *(const short8*)(base_ + (m_ * 16 + n16) * 8);            \
    }                                                                          \
    _Pragma("unroll")                                                          \
    for (int c_ = 0; c_ < 8; ++c_)                                             \
      _Pragma("unroll")                                                        \
      for (int m_ = 0; m_ < 4; ++m_)                                           \
        asm volatile("" : "+v"(a_[c_][m_]));                                   \
    _Pragma("unroll")                                                          \
    for (int c_ = 0; c_ < 8; ++c_)                                             \
      _Pragma("unroll")                                                        \
      for (int m_ = 0; m_ < 4; ++m_)                                           \
        _Pragma("unroll")                                                      \
        for (int g_ = 0; g_ < 4; ++g_)                                         \
          acc[m_][g_] = __builtin_amdgcn_mfma_f32_16x16x32_bf16(a_[c_][m_], (W)[g_][c_], acc[m_][g_], 0, 0, 0); \
  }

// cross-wave K reduction via LDS; after this, tot[g] = full-K sums for m=wv.
#define REDUCE_TOT()                                                           \
  _Pragma("unroll")                                                            \
  for (int m_ = 0; m_ < 4; ++m_) {                                             \
    if (m_ != wv) {                                                            \
      int slot_ = (m_ - (m_ > wv ? 1 : 0)) * 4;                                \
      _Pragma("unroll")                                                        \
      for (int g_ = 0; g_ < 4; ++g_)                                           \
        *(floatx4*)&red[wv][slot_ + g_][lane * 4] = acc[m_][g_];               \
    }                                                                          \
  }                                                                            \
  __syncthreads();                                                             \
  _Pragma("unroll")                                                            \
  for (int g_ = 0; g_ < 4; ++g_) tot[g_] = acc[wv][g_];                        \
  _Pragma("unroll")                                                            \
  for (int w2_ = 0; w2_ < 4; ++w2_) {                                          \
    if (w2_ != wv) {                                                           \
      int slot_ = (wv - (wv > w2_ ? 1 : 0)) * 4;                               \
      _Pragma("unroll")                                                        \
      for (int g_ = 0; g_ < 4; ++g_)                                           \
        tot[g_] += *(const floatx4*)&red[w2_][slot_ + g_][lane * 4];           \
    }                                                                          \
  }

// distributed flag barrier: flag[i] at FL[i*8] (32B stride). One writer per
// flag (atomic store, no RMW chain); wave-0's 64 lanes poll 64 flags in
// parallel (each lane a distinct dword) and combine with __all.
#define POLL1(FLA, TGTA)                                                       \
  if (wv == 0) {                                                               \
    int spins_ = 0;                                                            \
    for (;;) {                                                                 \
      unsigned va_ = ald((FLA) + lane * 8);                                    \
      if (__all((int)(va_ >= (TGTA)))) break;                                  \
      __builtin_amdgcn_s_sleep(1);                                             \
      if (++spins_ > (1 << 17)) break;                                         \
    }                                                                          \
  }
#define POLL2(FLA, TGTA, FLB, TGTB)                                            \
  if (wv == 0) {                                                               \
    int spins_ = 0;                                                            \
    for (;;) {                                                                 \
      unsigned va_ = ald((FLA) + lane * 8);                                    \
      unsigned vb_ = ald((FLB) + lane * 8);                                    \
      if (__all((int)((va_ >= (TGTA)) & (vb_ >= (TGTB))))) break;              \
      __builtin_amdgcn_s_sleep(1);                                             \
      if (++spins_ > (1 << 17)) break;                                         \
    }                                                                          \
  }

// ---------------- fused persistent 3-stage LSTM pipeline ----------------
// VERIFIED BEST (round 8: 1917 us total, fused 1737 us, 6.8 us/step).
// 192 WGs x 256 threads; group = blockIdx>>6: 0=L0 (h0 recurrence), 1=P1
// (G1 producer: h0(t+1) @ Wx1^T), 2=L1 (h1 recurrence). Every group is a
// K=1024 pass with its 128-VGPR weight slice register-resident.
// G1 ring: 8 rows x 512KB in dead Xbf space; scattered dword agent atomics
// (round-5 form, FROZEN: round 6 qword-shuffle packing was slower, round 7
// thread-major qword raced, round 9 second global ring hit MALL write
// amplification, round 10 LDS co-residence broke the 256-VGPR budget).
// Sync: per-WG flags, stride 8 dwords; store-only writers; 64-lane polls.
// Gating: L0(t): fl0 >= t. P1(t): fl0 >= t+1 (h0 row t+1) and fl1 >= t-7
// (ring slot free). L1(t): fl2 >= t+1 (G1[t] ready) and fl1 >= t (own row).
__global__ __launch_bounds__(256, 1) void lstm_fused(
    const u16* __restrict__ Wh0b,   // [4096][1024] bf16
    const u16* __restrict__ Wx1b,   // [4096][1024] bf16
    const u16* __restrict__ Wh1b,   // [4096][1024] bf16
    const u16* __restrict__ G,      // [16384][4096] bf16 (x@Wx0^T)
    const float* __restrict__ bias, // [2][4096]
    unsigned* H0u,                  // u32 blocked, 257 rows
    unsigned* H1u,
    unsigned* G1u,                  // ring: 8 x 131072 u32
    unsigned* FL,                   // fl0 @0, fl1 @512, fl2 @1024 (dwords)
    float* __restrict__ outp,       // [256*64*1024] fp32 (layer-1 output)
    float* __restrict__ hf,         // [2*64*1024] fp32
    float* __restrict__ cf) {       // [2*64*1024] fp32
  __shared__ float red[4][12][256];
  const int tid = threadIdx.x;
  const int wv = tid >> 6;
  const int lane = tid & 63;
  const int q = lane >> 4;
  const int n16 = lane & 15;
  const int gid = blockIdx.x >> 6;
  const int jb = blockIdx.x & 63;
  const int jg = (jb << 4) + n16;
  const int kq0 = wv << 8;
  unsigned* fl0 = FL;
  unsigned* fl1 = FL + 512;
  unsigned* fl2 = FL + 1024;
  const floatx4 vzero = {0.f, 0.f, 0.f, 0.f};

  if (gid == 0) {
    // ================= L0: layer-0 recurrence =================
    short8 wf[4][8];
#pragma unroll
    for (int g = 0; g < 4; ++g)
#pragma unroll
      for (int c = 0; c < 8; ++c)
        wf[g][c] = *(const short8*)(Wh0b + (size_t)(g * 1024 + jg) * 1024 + kq0 + c * 32 + q * 8);
#pragma unroll
    for (int g = 0; g < 4; ++g)
#pragma unroll
      for (int c = 0; c < 8; ++c) asm volatile("" : "+v"(wf[g][c]));

    float bs[4];
#pragma unroll
    for (int g = 0; g < 4; ++g) bs[g] = bias[g * 1024 + jg];
    float cst[4] = {0.f, 0.f, 0.f, 0.f};

    float gf[4][4];  // G fragment for m=wv tile
#pragma unroll
    for (int g = 0; g < 4; ++g)
#pragma unroll
      for (int r = 0; r < 4; ++r)
        gf[g][r] = b2f(G[(size_t)(wv * 16 + q * 4 + r) * 4096 + g * 1024 + jg]);

    for (int t = 0; t < NSTEP; ++t) {
      POLL1(fl0, (unsigned)t);   // peers done step t-1 -> h0 row t readable
      __syncthreads();

      floatx4 acc[4][4];
#pragma unroll
      for (int m = 0; m < 4; ++m)
#pragma unroll
        for (int g = 0; g < 4; ++g) acc[m][g] = vzero;
      GEMM_Q(H0u + (size_t)t * 32768, wf);

      floatx4 tot[4];
      REDUCE_TOT();

      unsigned* hnext = H0u + (size_t)(t + 1) * 32768 + jb * 512;
      float hsv[4];
#pragma unroll
      for (int r = 0; r < 4; ++r) {
        float pi = tot[0][r] + gf[0][r] + bs[0];
        float pf = tot[1][r] + gf[1][r] + bs[1];
        float po = tot[2][r] + gf[2][r] + bs[2];
        float pc = tot[3][r] + gf[3][r] + bs[3];
        float cn = sigf(pf) * cst[r] + sigf(pi) * tanhf_fast(pc);
        float h = sigf(po) * tanhf_fast(cn);
        cst[r] = cn;
        hsv[r] = h;
        int brow = wv * 16 + q * 4 + r;
        unsigned hv = f2b_rne(h);
        unsigned pv = (unsigned)__shfl_xor((int)hv, 1);
        if (!(n16 & 1)) ast(hnext + brow * 8 + (n16 >> 1), hv | (pv << 16));
      }

      __syncthreads();  // drain h atomic stores (compiler vmcnt(0) at barrier)
      if (tid == 0) ast(fl0 + jb * 8, (unsigned)(t + 1));

      // tail (off critical path): G prefetch for t+1, final h/c
      if (t + 1 < NSTEP) {
#pragma unroll
        for (int g = 0; g < 4; ++g)
#pragma unroll
          for (int r = 0; r < 4; ++r)
            gf[g][r] = b2f(G[(size_t)((t + 1) * 64 + wv * 16 + q * 4 + r) * 4096 + g * 1024 + jg]);
      }
      if (t == NSTEP - 1) {
#pragma unroll
        for (int r = 0; r < 4; ++r) {
          int brow = wv * 16 + q * 4 + r;
          hf[brow * 1024 + jg] = hsv[r];
          cf[brow * 1024 + jg] = cst[r];
        }
      }
    }
  } else if (gid == 1) {
    // ================= P1: G1 producer (h0(t+1) @ Wx1^T) =================
    short8 wf[4][8];
#pragma unroll
    for (int g = 0; g < 4; ++g)
#pragma unroll
      for (int c = 0; c < 8; ++c)
        wf[g][c] = *(const short8*)(Wx1b + (size_t)(g * 1024 + jg) * 1024 + kq0 + c * 32 + q * 8);
#pragma unroll
    for (int g = 0; g < 4; ++g)
#pragma unroll
      for (int c = 0; c < 8; ++c) asm volatile("" : "+v"(wf[g][c]));

    for (int t = 0; t < NSTEP; ++t) {
      unsigned tgtb = (t >= 8) ? (unsigned)(t - 7) : 0u;  // ring slot free
      POLL2(fl0, (unsigned)(t + 1), fl1, tgtb);
      __syncthreads();

      floatx4 acc[4][4];
#pragma unroll
      for (int m = 0; m < 4; ++m)
#pragma unroll
        for (int g = 0; g < 4; ++g) acc[m][g] = vzero;
      GEMM_Q(H0u + (size_t)(t + 1) * 32768, wf);

      floatx4 tot[4];
      REDUCE_TOT();

      // store G1[t] slice: blocked like h rows, per-jb 2048-dword block
      // (round-5 verified scattered-dword path — do not change)
      unsigned* g1o = G1u + (size_t)(t & 7) * 131072 + jb * 2048;
#pragma unroll
      for (int r = 0; r < 4; ++r) {
        int b = wv * 16 + q * 4 + r;
#pragma unroll
        for (int g = 0; g < 4; ++g) {
          unsigned v = f2b_rne(tot[g][r]);
          unsigned pv = (unsigned)__shfl_xor((int)v, 1);
          if (!(n16 & 1)) ast(g1o + g * 512 + b * 8 + (n16 >> 1), v | (pv << 16));
        }
      }

      __syncthreads();  // drain G1 stores
      if (tid == 0) ast(fl2 + jb * 8, (unsigned)(t + 1));
    }
  } else {
    // ================= L1: layer-1 recurrence =================
    short8 wf[4][8];
#pragma unroll
    for (int g = 0; g < 4; ++g)
#pragma unroll
      for (int c = 0; c < 8; ++c)
        wf[g][c] = *(const short8*)(Wh1b + (size_t)(g * 1024 + jg) * 1024 + kq0 + c * 32 + q * 8);
#pragma unroll
    for (int g = 0; g < 4; ++g)
#pragma unroll
      for (int c = 0; c < 8; ++c) asm volatile("" : "+v"(wf[g][c]));

    float bs[4];
#pragma unroll
    for (int g = 0; g < 4; ++g) bs[g] = bias[4096 + g * 1024 + jg];
    float cst[4] = {0.f, 0.f, 0.f, 0.f};

    for (int t = 0; t < NSTEP; ++t) {
      POLL2(fl2, (unsigned)(t + 1), fl1, (unsigned)t);
      __syncthreads();

      // G1 fragment: scattered dword atomic loads (round-5 verified path);
      // issued before the GEMM batch -> latency hides under the a_ pin drain.
      const unsigned* g1i = G1u + (size_t)(t & 7) * 131072 + jb * 2048;
      float gf[4][4];
#pragma unroll
      for (int g = 0; g < 4; ++g)
#pragma unroll
        for (int r = 0; r < 4; ++r) {
          int b = wv * 16 + q * 4 + r;
          unsigned dw = ald(g1i + g * 512 + b * 8 + (n16 >> 1));
          gf[g][r] = b2f((u16)(dw >> (16 * (n16 & 1))));
        }

      floatx4 acc[4][4];
#pragma unroll
      for (int m = 0; m < 4; ++m)
#pragma unroll
        for (int g = 0; g < 4; ++g) acc[m][g] = vzero;
      GEMM_Q(H1u + (size_t)t * 32768, wf);

      floatx4 tot[4];
      REDUCE_TOT();

      unsigned* hnext = H1u + (size_t)(t + 1) * 32768 + jb * 512;
      float hsv[4];
#pragma unroll
      for (int r = 0; r < 4; ++r) {
        float pi = tot[0][r] + gf[0][r] + bs[0];
        float pf = tot[1][r] + gf[1][r] + bs[1];
        float po = tot[2][r] + gf[2][r] + bs[2];
        float pc = tot[3][r] + gf[3][r] + bs[3];
        float cn = sigf(pf) * cst[r] + sigf(pi) * tanhf_fast(pc);
        float h = sigf(po) * tanhf_fast(cn);
        cst[r] = cn;
        hsv[r] = h;
        int brow = wv * 16 + q * 4 + r;
        unsigned hv = f2b_rne(h);
        unsigned pv = (unsigned)__shfl_xor((int)hv, 1);
        if (!(n16 & 1)) ast(hnext + brow * 8 + (n16 >> 1), hv | (pv << 16));
      }

      __syncthreads();  // drain h stores
      if (tid == 0) ast(fl1 + jb * 8, (unsigned)(t + 1));

      // tail: outputs (off critical path)
#pragma unroll
      for (int r = 0; r < 4; ++r) {
        int brow = wv * 16 + q * 4 + r;
        outp[((size_t)t * 64 + brow) * 1024 + jg] = hsv[r];
      }
      if (t == NSTEP - 1) {
#pragma unroll
        for (int r = 0; r < 4; ++r) {
          int brow = wv * 16 + q * 4 + r;
          hf[65536 + brow * 1024 + jg] = hsv[r];
          cf[65536 + brow * 1024 + jg] = cst[r];
        }
      }
    }
  }
}

// ---------------- launch ----------------
extern "C" void kernel_launch(void* const* d_in, const int* in_sizes, int n_in,
                              void* d_out, int out_size, void* d_ws, size_t ws_size,
                              hipStream_t stream) {
  const float* X  = (const float*)d_in[0];   // [256][64][1024]
  const float* Wx = (const float*)d_in[1];   // [2][4096][1024]
  const float* Wh = (const float*)d_in[2];   // [2][4096][1024]
  const float* b  = (const float*)d_in[3];   // [2][4096]
  float* out = (float*)d_out;

  char* ws = (char*)d_ws;
  u16* Xbf  = (u16*)(ws);                         // 33,554,432 B (dead after gemm_nt)
  unsigned* G1 = (unsigned*)(ws);                 // ring 8 x 512 KB = 4 MB (overlays dead Xbf)
  unsigned* FL = (unsigned*)(ws + 8388608);       // flags, 6 KB (overlays dead Xbf)
  u16* Wxbf = (u16*)(ws + 33554432);              // 16,777,216 B
  u16* Whbf = (u16*)(ws + 50331648);              // 16,777,216 B
  unsigned* H0 = (unsigned*)(ws + 67108864);      // 33,685,504 B (257*131072)
  unsigned* H1 = (unsigned*)(ws + 100794368);     // 33,685,504 B
  u16* G    = (u16*)(ws + 134479872);             // 134,217,728 B

  float* out_seq = out;                // 16,777,216 floats
  float* Hf = out + 16777216;          // 131,072 floats
  float* Cf = out + 16777216 + 131072; // 131,072 floats

  init_kernel<<<128, 256, 0, stream>>>(H0, H1);
  cast_kernel<<<2048, 256, 0, stream>>>(X, Xbf, 16777216 / 4);
  cast_kernel<<<2048, 256, 0, stream>>>(Wx, Wxbf, 8388608 / 4);
  cast_kernel<<<2048, 256, 0, stream>>>(Wh, Whbf, 8388608 / 4);

  // layer-0 input GEMM: G = X @ Wx0^T
  gemm_nt<<<4096, 256, 0, stream>>>(Xbf, Wxbf, G);

  // zero flags (region overlays Xbf, so must run after gemm_nt)
  init2_kernel<<<6, 256, 0, stream>>>(FL);

  // fused 3-stage pipeline: L0 | P1 (x@Wx1 producer) | L1
  lstm_fused<<<192, 256, 0, stream>>>(Whbf, Wxbf + 4194304, Whbf + 4194304, G, b,
                                      H0, H1, G1, FL, out_seq, Hf, Cf);
}